// Round 1
// 858.035 us; speedup vs baseline: 1.4305x; 1.4305x over previous
//
#include <hip/hip_runtime.h>

typedef __attribute__((ext_vector_type(8))) short  short8;   // MFMA A/B frag (8 bf16)
typedef __attribute__((ext_vector_type(4))) short  short4v;  // 8B LDS store
typedef __attribute__((ext_vector_type(4))) float  float4v;  // MFMA C/D frag
typedef __attribute__((ext_vector_type(4))) float  float4a;  // 16B global load

#define SEQ   2048
#define DHEAD 128
#define NH    32
#define NB    2
#define BM    64      // q rows per block (16 per wave x 4 waves)
#define BN    64      // k cols per tile

#define NEG_BIG (-1e30f)

__device__ __forceinline__ unsigned short f2bf(float x) {
    union { float f; unsigned int u; } un; un.f = x;
    unsigned int r = un.u + 0x7fffu + ((un.u >> 16) & 1u);   // round-to-nearest-even
    return (unsigned short)(r >> 16);
}

// XOR swizzle: permutes 16B slots within each 128B bank-row as a function of row.
// Balanced (conflict-free in throughput sense) for every access pattern below:
// b128 frag reads (rows vary with lane&15) and b64 staging writes (rows vary
// with lane at stride 1 or 4).
__device__ __forceinline__ int swz(int row, int colb) {
    return colb ^ ((((row & 7) ^ ((row >> 3) & 7)) << 4));
}

// Flash attention, causal. fp32 in/out, bf16 MFMA 16x16x32.
// SWAPPED score matmul: S^T = mfma(K_frag, Q_frag) so each lane owns ONE q-row
// (q = lane&15): softmax = 16 in-lane values + shfl_xor(16,32). P round-trip to
// LDS is 4x b64 stores per lane. V^T staged via register 4x4 transpose.
// Fragment layouts (guide §3, harness-verified in the parent kernel):
//   A-frag: A[m = lane&15][k = (lane>>4)*8 + j]
//   B-frag: B[k = (lane>>4)*8 + j][n = lane&15]
//   C/D   : D[row = (lane>>4)*4 + reg][col = lane&15]
__global__ __launch_bounds__(256, 4)
void attn_fwd(const float* __restrict__ Qg,
              const float* __restrict__ Kg,
              const float* __restrict__ Vg,
              float* __restrict__ Og)
{
    // sK [64 key][128 d] bf16, 256B/row, swizzled          = 16384 B
    // sV [128 d][64 key] bf16 (V^T), 128B/row, swizzled    = 16384 B
    // sP 4 waves x [16 q][64 key] bf16, swizzled           =  8192 B
    // sQ overlays sV (only used before the main loop)       total 40960 B -> 4 blocks/CU
    __shared__ __align__(16) char smem[40960];
    char* sKb = smem;
    char* sVb = smem + 16384;
    char* sPb = smem + 32768;
    char* sQb = sVb;

    const int tid  = threadIdx.x;
    const int w    = tid >> 6;
    const int lane = tid & 63;
    const int quad = lane >> 4;
    const int m16  = lane & 15;

    const int bid = blockIdx.x;
    const int qt  = (SEQ / BM - 1) - (bid & (SEQ / BM - 1));  // heavy q-tiles dispatch first
    const int bh  = bid >> 5;                                  // b*NH + h
    const int q0  = qt * BM;

    const float* Qp = Qg + (size_t)bh * SEQ * DHEAD;
    const float* Kp = Kg + (size_t)bh * SEQ * DHEAD;
    const float* Vp = Vg + (size_t)bh * SEQ * DHEAD;

    // ---- stage Q once (fp32 -> bf16, swizzled, b64 stores) ----
    for (int i = tid; i < BM * 32; i += 256) {
        int r  = i >> 5;
        int c4 = (i & 31) << 2;
        float4a v = *(const float4a*)(Qp + (size_t)(q0 + r) * DHEAD + c4);
        short4v t;
        t[0] = (short)f2bf(v[0]); t[1] = (short)f2bf(v[1]);
        t[2] = (short)f2bf(v[2]); t[3] = (short)f2bf(v[3]);
        *(short4v*)(sQb + r * 256 + swz(r, c4 * 2)) = t;
    }
    __syncthreads();

    // Q B-frags live in registers for the whole kernel (one q-row per lane)
    short8 qf[4];
    const int qrow = w * 16 + m16;
#pragma unroll
    for (int kc = 0; kc < 4; ++kc)
        qf[kc] = *(const short8*)(sQb + qrow * 256 + swz(qrow, kc * 64 + quad * 16));

    float4v accO[8];
#pragma unroll
    for (int i = 0; i < 8; ++i) accO[i] = (float4v){0.f, 0.f, 0.f, 0.f};
    float mst = NEG_BIG, lst = 0.f;              // per-lane state for q = qglob
    const float scale = 0.08838834764831845f;    // 1/sqrt(128)
    const int   qglob = q0 + w * 16 + m16;

    for (int kt = 0; kt <= qt; ++kt) {
        const int k0 = kt * BN;
        __syncthreads();   // prior LDS reads (incl. qf at kt==0) done before restage

        // ---- stage K (b64 swizzled stores) ----
        for (int i = tid; i < BN * 32; i += 256) {
            int r  = i >> 5;
            int c4 = (i & 31) << 2;
            float4a v = *(const float4a*)(Kp + (size_t)(k0 + r) * DHEAD + c4);
            short4v t;
            t[0] = (short)f2bf(v[0]); t[1] = (short)f2bf(v[1]);
            t[2] = (short)f2bf(v[2]); t[3] = (short)f2bf(v[3]);
            *(short4v*)(sKb + r * 256 + swz(r, c4 * 2)) = t;
        }
        // ---- stage V^T via register 4x4 transpose (b64 swizzled stores) ----
        for (int i = tid; i < 512; i += 256) {
            int kb = i >> 5;          // key block of 4
            int db = i & 31;          // d block of 4
            const float* src = Vp + (size_t)(k0 + kb * 4) * DHEAD + db * 4;
            float4a v0 = *(const float4a*)(src);
            float4a v1 = *(const float4a*)(src + DHEAD);
            float4a v2 = *(const float4a*)(src + 2 * DHEAD);
            float4a v3 = *(const float4a*)(src + 3 * DHEAD);
#pragma unroll
            for (int c = 0; c < 4; ++c) {
                short4v t;
                t[0] = (short)f2bf(v0[c]); t[1] = (short)f2bf(v1[c]);
                t[2] = (short)f2bf(v2[c]); t[3] = (short)f2bf(v3[c]);
                int row = db * 4 + c;                       // d index
                *(short4v*)(sVb + row * 128 + swz(row, kb * 8)) = t;
            }
        }
        __syncthreads();

        // ---- S^T = K Q^T: accS[nt][r] = S[q=qglob][key = k0 + nt*16 + quad*4 + r] ----
        float4v accS[4];
#pragma unroll
        for (int nt = 0; nt < 4; ++nt) accS[nt] = (float4v){0.f, 0.f, 0.f, 0.f};
#pragma unroll
        for (int kc = 0; kc < 4; ++kc)
#pragma unroll
            for (int nt = 0; nt < 4; ++nt) {
                int krow = nt * 16 + m16;
                short8 kf = *(const short8*)(sKb + krow * 256 + swz(krow, kc * 64 + quad * 16));
                accS[nt] = __builtin_amdgcn_mfma_f32_16x16x32_bf16(kf, qf[kc], accS[nt], 0, 0, 0);
            }

        // ---- scale + causal mask (diagonal tile only) ----
        if (kt == qt) {
#pragma unroll
            for (int nt = 0; nt < 4; ++nt)
#pragma unroll
                for (int r = 0; r < 4; ++r) {
                    int key = k0 + nt * 16 + quad * 4 + r;
                    float s = accS[nt][r] * scale;
                    accS[nt][r] = (key > qglob) ? NEG_BIG : s;
                }
        } else {
#pragma unroll
            for (int nt = 0; nt < 4; ++nt)
#pragma unroll
                for (int r = 0; r < 4; ++r) accS[nt][r] *= scale;
        }

        // ---- online softmax: 16 in-lane values, cross-quad via shfl_xor 16/32 ----
        float mx = accS[0][0];
#pragma unroll
        for (int nt = 0; nt < 4; ++nt)
#pragma unroll
            for (int r = 0; r < 4; ++r) mx = fmaxf(mx, accS[nt][r]);
        mx = fmaxf(mx, __shfl_xor(mx, 16));
        mx = fmaxf(mx, __shfl_xor(mx, 32));
        float mnew  = fmaxf(mst, mx);
        float alpha = __expf(mst - mnew);
        mst = mnew;
        float rs = 0.f;
#pragma unroll
        for (int nt = 0; nt < 4; ++nt)
#pragma unroll
            for (int r = 0; r < 4; ++r) {
                float p = __expf(accS[nt][r] - mnew);
                accS[nt][r] = p;
                rs += p;
            }
        rs += __shfl_xor(rs, 16);
        rs += __shfl_xor(rs, 32);
        lst = lst * alpha + rs;

        // ---- rescale O (alpha for C-row quad*4+r lives at lane with m16 == quad*4+r) ----
        float alphaO[4];
#pragma unroll
        for (int r = 0; r < 4; ++r)
            alphaO[r] = __shfl(alpha, (quad << 4) | (quad * 4 + r));
#pragma unroll
        for (int dt = 0; dt < 8; ++dt)
#pragma unroll
            for (int r = 0; r < 4; ++r) accO[dt][r] *= alphaO[r];

        // ---- P -> per-wave LDS (4x b64 stores), read back as A-frags ----
        char* pwb = sPb + w * 2048;
#pragma unroll
        for (int nt = 0; nt < 4; ++nt) {
            short4v t;
            t[0] = (short)f2bf(accS[nt][0]); t[1] = (short)f2bf(accS[nt][1]);
            t[2] = (short)f2bf(accS[nt][2]); t[3] = (short)f2bf(accS[nt][3]);
            *(short4v*)(pwb + m16 * 128 + swz(m16, nt * 32 + quad * 8)) = t;
        }
        short8 pf[2];
#pragma unroll
        for (int kc2 = 0; kc2 < 2; ++kc2)
            pf[kc2] = *(const short8*)(pwb + m16 * 128 + swz(m16, kc2 * 64 + quad * 16));

        // ---- O += P V ----
#pragma unroll
        for (int kc2 = 0; kc2 < 2; ++kc2)
#pragma unroll
            for (int dt = 0; dt < 8; ++dt) {
                int vrow = dt * 16 + m16;
                short8 vf = *(const short8*)(sVb + vrow * 128 + swz(vrow, kc2 * 64 + quad * 16));
                accO[dt] = __builtin_amdgcn_mfma_f32_16x16x32_bf16(pf[kc2], vf, accO[dt], 0, 0, 0);
            }
    }

    // ---- epilogue: out[b][q][h*128 + d], fp32 ----
    const int b = bh >> 5;
    const int h = bh & 31;
    float il = 1.0f / lst;
    float invlO[4];
#pragma unroll
    for (int r = 0; r < 4; ++r)
        invlO[r] = __shfl(il, (quad << 4) | (quad * 4 + r));
#pragma unroll
    for (int dt = 0; dt < 8; ++dt)
#pragma unroll
        for (int r = 0; r < 4; ++r) {
            int q = q0 + w * 16 + quad * 4 + r;
            int d = dt * 16 + m16;
            Og[(size_t)(b * SEQ + q) * (NH * DHEAD) + h * DHEAD + d] = accO[dt][r] * invlO[r];
        }
}

extern "C" void kernel_launch(void* const* d_in, const int* in_sizes, int n_in,
                              void* d_out, int out_size, void* d_ws, size_t ws_size,
                              hipStream_t stream) {
    const float* Q = (const float*)d_in[0];
    const float* K = (const float*)d_in[1];
    const float* V = (const float*)d_in[2];
    float* O = (float*)d_out;
    dim3 grid((SEQ / BM) * NB * NH);
    attn_fwd<<<grid, 256, 0, stream>>>(Q, K, V, O);
}